// Round 5
// baseline (456.493 us; speedup 1.0000x reference)
//
#include <hip/hip_runtime.h>
#include <hip/hip_bf16.h>

#define B_ 8
#define C_ 320
#define N_ 13824      // 24^3
#define NT 128        // positions per block tile
#define L_ 77
#define LP 80         // L padded for 16-col tiles
#define LV 96         // L padded for K=96 contraction
#define CTXD 768
#define CPG 10        // channels per group (320/32)
#define EPS_ 1e-5f
#define SCALE_ 0.05590169943749474f   // 320^-0.5

typedef __attribute__((__ext_vector_type__(4))) float f32x4;
typedef __attribute__((__ext_vector_type__(8))) short s16x8;

// ws byte offsets
#define WS_ACCUM 0              // f32[8][32][2] = 2048 B
#define WS_T     2048           // f32[8][80]    = 2560 B
#define WS_KST   4608           // bf16[8][80][320] = 409600 B  (k scaled, [l][o])
#define WS_VST   414208         // bf16[8][80][320]             (v, [l][o])
#define WS_K2T   823808         // bf16[8][80][320]             (Wq^T k, [l][c])
#define WS_V2    1233408        // bf16[8][320][96]             (Wo v, [c][l])
#define WS_WQT   1724928        // bf16[320][320]  Wq transposed [c][o]
#define WS_WO    1929728        // bf16[320][320]  Wo [c'][o]

__device__ __forceinline__ unsigned short f2bf(float f) {
  union { float f; unsigned u; } v; v.f = f;
  unsigned r = v.u + 0x7FFFu + ((v.u >> 16) & 1u);
  return (unsigned short)(r >> 16);
}
__device__ __forceinline__ float bf2f(unsigned short s) {
  union { unsigned u; float f; } v; v.u = ((unsigned)s) << 16;
  return v.f;
}
// load 8 consecutive f32 -> bf16x8 fragment
__device__ __forceinline__ s16x8 cvt8(const float* p) {
  f32x4 a = *reinterpret_cast<const f32x4*>(p);
  f32x4 b = *reinterpret_cast<const f32x4*>(p + 4);
  s16x8 r;
  r[0] = (short)f2bf(a[0]); r[1] = (short)f2bf(a[1]);
  r[2] = (short)f2bf(a[2]); r[3] = (short)f2bf(a[3]);
  r[4] = (short)f2bf(b[0]); r[5] = (short)f2bf(b[1]);
  r[6] = (short)f2bf(b[2]); r[7] = (short)f2bf(b[3]);
  return r;
}
__device__ __forceinline__ f32x4 MFMA(s16x8 a, s16x8 b, f32x4 c) {
  return __builtin_amdgcn_mfma_f32_16x16x32_bf16(a, b, c, 0, 0, 0);
}

// ---------------- PREP: wconv (blocks 0..399) + kv1 l-split (blocks 400..599) --------
__global__ __launch_bounds__(256) void prep_kernel(const float* __restrict__ Wq,
                                                   const float* __restrict__ Wo,
                                                   const float* __restrict__ ctx,
                                                   const float* __restrict__ Wk,
                                                   const float* __restrict__ bk,
                                                   const float* __restrict__ Wv,
                                                   const float* __restrict__ bv,
                                                   unsigned short* __restrict__ wqT,
                                                   unsigned short* __restrict__ wo_bf,
                                                   unsigned short* __restrict__ kst,
                                                   unsigned short* __restrict__ vst,
                                                   float* __restrict__ zws) {
  int bid = blockIdx.x;
  if (bid < 400) {
    int t = bid * 256 + threadIdx.x;
    if (t >= C_ * C_) return;
    int o = t / C_, c = t - o * C_;
    wqT[c * C_ + o] = f2bf(Wq[t]);
    wo_bf[t] = f2bf(Wo[t]);
    return;
  }
  int kb = bid - 400;                       // 0..199
  // zero accum (512 f32) + tbuf (640 f32) = 1152 floats at ws[0..4608)
  { int t = kb * 256 + threadIdx.x; if (t < 1152) zws[t] = 0.f; }
  int lt = kb % 5;                          // l-tile 0..4
  int kb5 = kb / 5;                         // 0..39
  int b = kb5 / 5;
  int oc = kb5 % 5;                         // 64-row chunk of outputs
  int w = threadIdx.x >> 6, lane = threadIdx.x & 63;
  int r = lane & 15, h = lane >> 4;
  int o_row = oc * 64 + w * 16 + r;         // A-fragment row
  int l = lt * 16 + r;                      // B col / D col
  bool lok = (l < L_);
  f32x4 ak = {}, av = {};
  for (int ks = 0; ks < 24; ++ks) {
    int c0 = ks * 32 + h * 8;
    s16x8 aWk = cvt8(Wk + o_row * CTXD + c0);
    s16x8 aWv = cvt8(Wv + o_row * CTXD + c0);
    s16x8 bfr = {0,0,0,0,0,0,0,0};
    if (lok) bfr = cvt8(ctx + (b * L_ + l) * CTXD + c0);
    ak = MFMA(aWk, bfr, ak);
    av = MFMA(aWv, bfr, av);
  }
#pragma unroll
  for (int j = 0; j < 4; ++j) {
    int o = oc * 64 + w * 16 + h * 4 + j;
    float bkv = bk[o], bvv = bv[o];
    // pad rows l in [77,80) must be EXPLICIT zeros (kv2 reads them)
    unsigned short kw = lok ? f2bf(SCALE_ * (ak[j] + bkv)) : (unsigned short)0;
    unsigned short vw = lok ? f2bf(av[j] + bvv) : (unsigned short)0;
    kst[(b * LP + l) * C_ + o] = kw;
    vst[(b * LP + l) * C_ + o] = vw;
  }
}

// ---------------- KV2: k2T[l][c] = (Wq^T k_s), v2[c][l] = Wo v_s, t[l] = bq . k_s[:,l] --
__global__ __launch_bounds__(256) void kv2_kernel(const unsigned short* __restrict__ wqT,
                                                  const unsigned short* __restrict__ wo_bf,
                                                  const unsigned short* __restrict__ kst,
                                                  const unsigned short* __restrict__ vst,
                                                  const float* __restrict__ bq,
                                                  float* __restrict__ tbuf,
                                                  unsigned short* __restrict__ k2T,
                                                  unsigned short* __restrict__ v2) {
  int b = blockIdx.x / 5;
  int cc = blockIdx.x % 5;
  int w = threadIdx.x >> 6, lane = threadIdx.x & 63;
  int r = lane & 15, h = lane >> 4;
  int c_row = cc * 64 + w * 16 + r;
  f32x4 a2[5] = {}, av[5] = {};
#pragma unroll
  for (int ks = 0; ks < 10; ++ks) {
    int o0 = ks * 32 + h * 8;
    s16x8 aq = *reinterpret_cast<const s16x8*>(wqT + c_row * C_ + o0);
    s16x8 ao = *reinterpret_cast<const s16x8*>(wo_bf + c_row * C_ + o0);
#pragma unroll
    for (int nt = 0; nt < 5; ++nt) {
      int l = nt * 16 + r;
      s16x8 bk_ = *reinterpret_cast<const s16x8*>(kst + (b * LP + l) * C_ + o0);
      s16x8 bv_ = *reinterpret_cast<const s16x8*>(vst + (b * LP + l) * C_ + o0);
      a2[nt] = MFMA(aq, bk_, a2[nt]);
      av[nt] = MFMA(ao, bv_, av[nt]);
    }
  }
#pragma unroll
  for (int j = 0; j < 4; ++j) {
    int c = cc * 64 + w * 16 + h * 4 + j;
#pragma unroll
    for (int nt = 0; nt < 5; ++nt) {
      int l = nt * 16 + r;
      k2T[(b * LP + l) * C_ + c] = f2bf(a2[nt][j]);
      v2[(b * C_ + c) * LV + l] = f2bf(av[nt][j]);
    }
  }
  // zero v2 pad cols l in [80,96) (read by GEMM-H K=96; must not be garbage)
  {
    int c = cc * 64 + w * 16 + (lane >> 2);
    int l = 80 + (lane & 3) * 4;
    unsigned long long* p = (unsigned long long*)(v2 + ((long)(b * C_ + c)) * LV + l);
    *p = 0ull;
  }
  // t[l] = sum_o bq[o] * k_s[l][o]   (k_s already scaled; pad rows are zero)
  if (cc == 0 && threadIdx.x < LP) {
    int l = threadIdx.x;
    float acc = 0.f;
    for (int o8 = 0; o8 < C_; o8 += 8) {
      s16x8 kv = *reinterpret_cast<const s16x8*>(kst + (b * LP + l) * C_ + o8);
#pragma unroll
      for (int j = 0; j < 8; ++j) acc += bq[o8 + j] * bf2f((unsigned short)kv[j]);
    }
    tbuf[b * LP + l] = acc;
  }
}

// ---------------- MAIN: 128-pos tile, 512 threads, LDS overlay, bf16 packed h -------
__global__ __launch_bounds__(512, 8) void main_kernel(const float* __restrict__ x,
                                                      const unsigned short* __restrict__ k2T,
                                                      const unsigned short* __restrict__ v2,
                                                      const float* __restrict__ tbuf,
                                                      const float* __restrict__ bo,
                                                      float* __restrict__ accum,
                                                      float* __restrict__ hout) {
  // LDS overlay: region A = union{ xbuf[2][128][40] (20480 B, live in GEMM-S),
  //                                wT[128][104]     (26624 B, live softmax->GEMM-H) }
  //              region B = ch[2][320][2] f32 (5120 B)   total 31744 B
  __shared__ __align__(16) char smem[26624 + 5120];
  unsigned short (*xbuf)[NT][40] = (unsigned short (*)[NT][40])smem;
  unsigned short (*wT)[104]      = (unsigned short (*)[104])smem;
  float (*ch)[C_][2]             = (float (*)[C_][2])(smem + 26624);
  // XCD-chunked bijective swizzle: 864 = 8 * 108; XCD k gets one batch's tiles in order
  int bid = blockIdx.x;
  int swz = (bid & 7) * 108 + (bid >> 3);
  int b = swz / 108;
  int n0 = (swz % 108) * NT;
  int tid = threadIdx.x;
  int w = tid >> 6, lane = tid & 63, r = lane & 15, h = lane >> 4;
  // staging mapping: thread owns channel pair (2cp, 2cp+1), n-range 4s..4s+3
  int s_ = tid & 31;
  int cp = tid >> 5;
  const float* xg = x + (long)b * C_ * N_ + n0;
  char* xb0 = (char*)&xbuf[0][0][0];
  char* xb1 = (char*)&xbuf[1][0][0];
  int wswz = (s_ & 3) << 4;                   // XOR key ((n>>2)&3)<<4
  int wbyte = (4 * s_) * 80 + cp * 4;         // base byte (q adds 80 each)
  int arow = w * 16 + r;
  int abyte = (arow * 80 + h * 16) ^ (((arow >> 2) & 3) << 4);
  const unsigned short* k2b = k2T + (long)b * LP * C_;

  // ---- prolog: load+write chunk0, load chunk1, preload k2T chunk0 fragments ----
  f32x4 ra[2], rb[2];
  {
    const float* p = xg + (long)(2 * cp) * N_ + 4 * s_;
    ra[0] = *reinterpret_cast<const f32x4*>(p);
    rb[0] = *reinterpret_cast<const f32x4*>(p + N_);
  }
#pragma unroll
  for (int q = 0; q < 4; ++q) {
    unsigned pk = (unsigned)f2bf(ra[0][q]) | ((unsigned)f2bf(rb[0][q]) << 16);
    *reinterpret_cast<unsigned*>(xb0 + ((wbyte + q * 80) ^ wswz)) = pk;
  }
  {
    const float* p = xg + (long)(32 + 2 * cp) * N_ + 4 * s_;
    ra[1] = *reinterpret_cast<const f32x4*>(p);
    rb[1] = *reinterpret_cast<const f32x4*>(p + N_);
  }
  s16x8 kf[5];
#pragma unroll
  for (int nt = 0; nt < 5; ++nt)
    kf[nt] = *reinterpret_cast<const s16x8*>(k2b + (nt * 16 + r) * C_ + h * 8);
  __syncthreads();

  // ---- GEMM-S over 10 chunks of 32 channels (k2T one-step register pipeline) ----
  f32x4 sacc[5] = {};
#pragma unroll
  for (int ks = 0; ks < 10; ++ks) {
    if (ks < 8) {   // prefetch x chunk ks+2 into the reg set just freed
      const float* p = xg + (long)((ks + 2) * 32 + 2 * cp) * N_ + 4 * s_;
      ra[ks & 1] = *reinterpret_cast<const f32x4*>(p);
      rb[ks & 1] = *reinterpret_cast<const f32x4*>(p + N_);
    }
    s16x8 kn[5];
    if (ks < 9) {   // prefetch next chunk's k2T fragments (L2-hot, hidden under MFMA)
#pragma unroll
      for (int nt = 0; nt < 5; ++nt)
        kn[nt] = *reinterpret_cast<const s16x8*>(
            k2b + (nt * 16 + r) * C_ + (ks + 1) * 32 + h * 8);
    }
    const char* xb = (ks & 1) ? xb1 : xb0;
    s16x8 a = *reinterpret_cast<const s16x8*>(xb + abyte);
#pragma unroll
    for (int nt = 0; nt < 5; ++nt) sacc[nt] = MFMA(a, kf[nt], sacc[nt]);
    if (ks < 9) {   // write x chunk ks+1 into the other buffer
      char* xw = (ks & 1) ? xb0 : xb1;
      f32x4 va = ra[(ks + 1) & 1], vb = rb[(ks + 1) & 1];
#pragma unroll
      for (int q = 0; q < 4; ++q) {
        unsigned pk = (unsigned)f2bf(va[q]) | ((unsigned)f2bf(vb[q]) << 16);
        *reinterpret_cast<unsigned*>(xw + ((wbyte + q * 80) ^ wswz)) = pk;
      }
    }
    __syncthreads();
#pragma unroll
    for (int nt = 0; nt < 5; ++nt) kf[nt] = kn[nt];
  }

  // ---- + t, softmax over l ----
#pragma unroll
  for (int nt = 0; nt < 5; ++nt) {
    float tl = tbuf[b * LP + nt * 16 + r];
#pragma unroll
    for (int j = 0; j < 4; ++j) sacc[nt][j] += tl;
  }
  bool maskpad = (r >= 13);   // col 64+r >= 77
#pragma unroll
  for (int j = 0; j < 4; ++j) {
    float m = -1e30f;
#pragma unroll
    for (int nt = 0; nt < 5; ++nt) {
      float v = (nt == 4 && maskpad) ? -1e30f : sacc[nt][j];
      m = fmaxf(m, v);
    }
    for (int d = 1; d < 16; d <<= 1) m = fmaxf(m, __shfl_xor(m, d));
    float e[5]; float sum = 0.f;
#pragma unroll
    for (int nt = 0; nt < 5; ++nt) {
      float v = (nt == 4 && maskpad) ? 0.f : __expf(sacc[nt][j] - m);
      e[nt] = v; sum += v;
    }
    for (int d = 1; d < 16; d <<= 1) sum += __shfl_xor(sum, d);
    float inv = 1.f / sum;
    int n = w * 16 + h * 4 + j;
#pragma unroll
    for (int nt = 0; nt < 5; ++nt) wT[n][nt * 16 + r] = f2bf(e[nt] * inv);
  }
  // zero wT cols 80..95 (K=96 contraction pad): 512 threads cover [128][16]
  {
    int row = tid >> 2, c0 = 80 + (tid & 3) * 4;
    *reinterpret_cast<unsigned*>(&wT[row][c0]) = 0u;
    *reinterpret_cast<unsigned*>(&wT[row][c0 + 2]) = 0u;
  }
  __syncthreads();

  // ---- GEMM-H: wave = (n-half nh, c-chunk cc4); h[80 c][64 n], K=96 over l ----
  int nh = w >> 2;          // 0/1: n-half
  int cc4 = w & 3;          // c-chunk of 80
  f32x4 acc[5][4] = {};
#pragma unroll
  for (int ks = 0; ks < 3; ++ks) {
    int l0 = ks * 32 + h * 8;
    s16x8 bfr[4];
#pragma unroll
    for (int nt = 0; nt < 4; ++nt)
      bfr[nt] = *reinterpret_cast<const s16x8*>(&wT[nh * 64 + nt * 16 + r][l0]);
#pragma unroll
    for (int mt = 0; mt < 5; ++mt) {
      int c = cc4 * 80 + mt * 16 + r;
      s16x8 a = *reinterpret_cast<const s16x8*>(v2 + ((long)(b * C_ + c)) * LV + l0);
#pragma unroll
      for (int nt = 0; nt < 4; ++nt) acc[mt][nt] = MFMA(a, bfr[nt], acc[mt][nt]);
    }
  }
  // ---- epilogue: + bo + residual (fp32 global, L2-hot), bf16 packed store, stats ----
#pragma unroll
  for (int mt = 0; mt < 5; ++mt) {
    int cb = cc4 * 80 + mt * 16 + h * 4;
    float bov[4];
#pragma unroll
    for (int j = 0; j < 4; ++j) bov[j] = bo[cb + j];
    float sv[4] = {0.f, 0.f, 0.f, 0.f}, sq[4] = {0.f, 0.f, 0.f, 0.f};
#pragma unroll
    for (int nt = 0; nt < 4; ++nt) {
      int n = nh * 64 + nt * 16 + r;
      const float* xp = xg + (long)cb * N_ + n;
#pragma unroll
      for (int j = 0; j < 4; ++j) {
        float val = acc[mt][nt][j] + bov[j] + xp[(long)j * N_];
        // bf16 packed store: chunk 2048 elems; bf16 of chunk sits in first 4 KB
        // of that chunk's 8 KB f32 region (self-contained for norm blocks)
        long e = ((long)b * C_ + cb + j) * N_ + n0 + n;
        *reinterpret_cast<unsigned short*>(
            (char*)hout + ((e >> 11) << 13) + ((e & 2047) << 1)) = f2bf(val);
        sv[j] += val; sq[j] += val * val;
      }
    }
#pragma unroll
    for (int j = 0; j < 4; ++j) {
      for (int d = 1; d < 16; d <<= 1) {
        sv[j] += __shfl_xor(sv[j], d);
        sq[j] += __shfl_xor(sq[j], d);
      }
      if (r == 0) { ch[nh][cb + j][0] = sv[j]; ch[nh][cb + j][1] = sq[j]; }
    }
  }
  __syncthreads();
  if (tid < 32) {
    float s0 = 0.f, s1 = 0.f;
#pragma unroll
    for (int i = 0; i < CPG; ++i) {
      int c = tid * CPG + i;
      s0 += ch[0][c][0] + ch[1][c][0];
      s1 += ch[0][c][1] + ch[1][c][1];
    }
    atomicAdd(&accum[b * 64 + tid * 2], s0);
    atomicAdd(&accum[b * 64 + tid * 2 + 1], s1);
  }
}

// ---------------- normalize + affine + swish: bf16 packed in -> f32 out -------------
__global__ __launch_bounds__(256) void norm_kernel(float* __restrict__ hout,
                                                   const float* __restrict__ accum,
                                                   const float* __restrict__ gamma,
                                                   const float* __restrict__ beta) {
  long idx0 = (long)blockIdx.x * 2048;
  int t = threadIdx.x;
  // thread t's 8 elements: idx0 + t*8 .. +8 (bf16 at chunk-local byte t*16)
  s16x8 hv = *reinterpret_cast<const s16x8*>((const char*)hout + idx0 * 4 + t * 16);
  __syncthreads();   // all bf16 reads complete before any f32 overwrite (intra-chunk)
  long idx = idx0 + (long)t * 8;
  int b = (int)(idx / ((long)C_ * N_));
  long rem = idx - (long)b * C_ * N_;
  int c = (int)(rem / N_);     // 8-run never crosses a channel row (8 | 13824)
  int g = c / CPG;
  float s0 = accum[b * 64 + g * 2], s1 = accum[b * 64 + g * 2 + 1];
  const float invc = 1.f / 138240.f;   // 1 / (CPG * N_)
  float mu = s0 * invc;
  float var = s1 * invc - mu * mu;
  float rstd = rsqrtf(var + EPS_);
  float ga = gamma[c], be = beta[c];
  f32x4 v0, v1;
#pragma unroll
  for (int q = 0; q < 4; ++q) {
    float y = (bf2f((unsigned short)hv[q]) - mu) * rstd * ga + be;
    v0[q] = y / (1.f + __expf(-y));
    float z = (bf2f((unsigned short)hv[q + 4]) - mu) * rstd * ga + be;
    v1[q] = z / (1.f + __expf(-z));
  }
  *reinterpret_cast<f32x4*>(hout + idx) = v0;
  *reinterpret_cast<f32x4*>(hout + idx + 4) = v1;
}

extern "C" void kernel_launch(void* const* d_in, const int* in_sizes, int n_in,
                              void* d_out, int out_size, void* d_ws, size_t ws_size,
                              hipStream_t stream) {
  const float* x     = (const float*)d_in[0];
  const float* ctx   = (const float*)d_in[1];
  const float* Wq    = (const float*)d_in[2];
  const float* bq    = (const float*)d_in[3];
  const float* Wk    = (const float*)d_in[4];
  const float* bk    = (const float*)d_in[5];
  const float* Wv    = (const float*)d_in[6];
  const float* bv    = (const float*)d_in[7];
  const float* Wo    = (const float*)d_in[8];
  const float* bo    = (const float*)d_in[9];
  const float* gamma = (const float*)d_in[10];
  const float* beta  = (const float*)d_in[11];
  float* out = (float*)d_out;
  char* ws = (char*)d_ws;

  float* accum = (float*)(ws + WS_ACCUM);
  float* tbuf  = (float*)(ws + WS_T);
  unsigned short* kst  = (unsigned short*)(ws + WS_KST);
  unsigned short* vst  = (unsigned short*)(ws + WS_VST);
  unsigned short* k2T  = (unsigned short*)(ws + WS_K2T);
  unsigned short* v2   = (unsigned short*)(ws + WS_V2);
  unsigned short* wqT  = (unsigned short*)(ws + WS_WQT);
  unsigned short* wo_b = (unsigned short*)(ws + WS_WO);

  prep_kernel<<<dim3(600), dim3(256), 0, stream>>>(Wq, Wo, ctx, Wk, bk, Wv, bv,
                                                   wqT, wo_b, kst, vst, (float*)ws);
  kv2_kernel<<<dim3(40), dim3(256), 0, stream>>>(wqT, wo_b, kst, vst, bq, tbuf, k2T, v2);
  main_kernel<<<dim3(864), dim3(512), 0, stream>>>(x, k2T, v2, tbuf, bo, accum, out);
  norm_kernel<<<dim3(17280), dim3(256), 0, stream>>>(out, accum, gamma, beta);
}

// Round 6
// 194.407 us; speedup vs baseline: 2.3481x; 2.3481x over previous
//
#include <hip/hip_runtime.h>
#include <hip/hip_bf16.h>

#define B_ 8
#define C_ 320
#define N_ 13824      // 24^3
#define NT 128        // positions per block tile
#define L_ 77
#define LP 80         // L padded for 16-col tiles
#define LV 96         // L padded for K=96 contraction
#define CTXD 768
#define CPG 10        // channels per group (320/32)
#define EPS_ 1e-5f
#define SCALE_ 0.05590169943749474f   // 320^-0.5
#define WTP 120       // wT padded cols (240 B rows: 2-way-free LDS reads)

typedef __attribute__((__ext_vector_type__(4))) float f32x4;
typedef __attribute__((__ext_vector_type__(8))) short s16x8;

// ws byte offsets
#define WS_ACCUM 0              // f32[8][32][2] = 2048 B
#define WS_T     2048           // f32[8][80]    = 2560 B
#define WS_KST   4608           // bf16[8][80][320] = 409600 B  (k scaled, [l][o])
#define WS_VST   414208         // bf16[8][80][320]             (v, [l][o])
#define WS_K2T   823808         // bf16[8][80][320]             (Wq^T k, [l][c])
#define WS_V2    1233408        // bf16[8][320][96]             (Wo v, [c][l])
#define WS_WQT   1724928        // bf16[320][320]  Wq transposed [c][o]
#define WS_WO    1929728        // bf16[320][320]  Wo [c'][o]

__device__ __forceinline__ unsigned short f2bf(float f) {
  union { float f; unsigned u; } v; v.f = f;
  unsigned r = v.u + 0x7FFFu + ((v.u >> 16) & 1u);
  return (unsigned short)(r >> 16);
}
__device__ __forceinline__ float bf2f(unsigned short s) {
  union { unsigned u; float f; } v; v.u = ((unsigned)s) << 16;
  return v.f;
}
// load 8 consecutive f32 -> bf16x8 fragment
__device__ __forceinline__ s16x8 cvt8(const float* p) {
  f32x4 a = *reinterpret_cast<const f32x4*>(p);
  f32x4 b = *reinterpret_cast<const f32x4*>(p + 4);
  s16x8 r;
  r[0] = (short)f2bf(a[0]); r[1] = (short)f2bf(a[1]);
  r[2] = (short)f2bf(a[2]); r[3] = (short)f2bf(a[3]);
  r[4] = (short)f2bf(b[0]); r[5] = (short)f2bf(b[1]);
  r[6] = (short)f2bf(b[2]); r[7] = (short)f2bf(b[3]);
  return r;
}
__device__ __forceinline__ f32x4 MFMA(s16x8 a, s16x8 b, f32x4 c) {
  return __builtin_amdgcn_mfma_f32_16x16x32_bf16(a, b, c, 0, 0, 0);
}

// ---------------- PREP: wconv (blocks 0..399) + kv1 l-split (blocks 400..599) --------
__global__ __launch_bounds__(256) void prep_kernel(const float* __restrict__ Wq,
                                                   const float* __restrict__ Wo,
                                                   const float* __restrict__ ctx,
                                                   const float* __restrict__ Wk,
                                                   const float* __restrict__ bk,
                                                   const float* __restrict__ Wv,
                                                   const float* __restrict__ bv,
                                                   unsigned short* __restrict__ wqT,
                                                   unsigned short* __restrict__ wo_bf,
                                                   unsigned short* __restrict__ kst,
                                                   unsigned short* __restrict__ vst,
                                                   float* __restrict__ zws) {
  int bid = blockIdx.x;
  if (bid < 400) {
    int t = bid * 256 + threadIdx.x;
    if (t >= C_ * C_) return;
    int o = t / C_, c = t - o * C_;
    wqT[c * C_ + o] = f2bf(Wq[t]);
    wo_bf[t] = f2bf(Wo[t]);
    return;
  }
  int kb = bid - 400;                       // 0..199
  // zero accum (512 f32) + tbuf (640 f32) = 1152 floats at ws[0..4608)
  { int t = kb * 256 + threadIdx.x; if (t < 1152) zws[t] = 0.f; }
  int lt = kb % 5;                          // l-tile 0..4
  int kb5 = kb / 5;                         // 0..39
  int b = kb5 / 5;
  int oc = kb5 % 5;                         // 64-row chunk of outputs
  int w = threadIdx.x >> 6, lane = threadIdx.x & 63;
  int r = lane & 15, h = lane >> 4;
  int o_row = oc * 64 + w * 16 + r;         // A-fragment row
  int l = lt * 16 + r;                      // B col / D col
  bool lok = (l < L_);
  f32x4 ak = {}, av = {};
  for (int ks = 0; ks < 24; ++ks) {
    int c0 = ks * 32 + h * 8;
    s16x8 aWk = cvt8(Wk + o_row * CTXD + c0);
    s16x8 aWv = cvt8(Wv + o_row * CTXD + c0);
    s16x8 bfr = {0,0,0,0,0,0,0,0};
    if (lok) bfr = cvt8(ctx + (b * L_ + l) * CTXD + c0);
    ak = MFMA(aWk, bfr, ak);
    av = MFMA(aWv, bfr, av);
  }
#pragma unroll
  for (int j = 0; j < 4; ++j) {
    int o = oc * 64 + w * 16 + h * 4 + j;
    float bkv = bk[o], bvv = bv[o];
    // pad rows l in [77,80) must be EXPLICIT zeros (kv2 reads them)
    unsigned short kw = lok ? f2bf(SCALE_ * (ak[j] + bkv)) : (unsigned short)0;
    unsigned short vw = lok ? f2bf(av[j] + bvv) : (unsigned short)0;
    kst[(b * LP + l) * C_ + o] = kw;
    vst[(b * LP + l) * C_ + o] = vw;
  }
}

// ---------------- KV2: k2T[l][c] = (Wq^T k_s), v2[c][l] = Wo v_s, t[l] = bq . k_s[:,l] --
__global__ __launch_bounds__(256) void kv2_kernel(const unsigned short* __restrict__ wqT,
                                                  const unsigned short* __restrict__ wo_bf,
                                                  const unsigned short* __restrict__ kst,
                                                  const unsigned short* __restrict__ vst,
                                                  const float* __restrict__ bq,
                                                  float* __restrict__ tbuf,
                                                  unsigned short* __restrict__ k2T,
                                                  unsigned short* __restrict__ v2) {
  int b = blockIdx.x / 5;
  int cc = blockIdx.x % 5;
  int w = threadIdx.x >> 6, lane = threadIdx.x & 63;
  int r = lane & 15, h = lane >> 4;
  int c_row = cc * 64 + w * 16 + r;
  f32x4 a2[5] = {}, av[5] = {};
#pragma unroll
  for (int ks = 0; ks < 10; ++ks) {
    int o0 = ks * 32 + h * 8;
    s16x8 aq = *reinterpret_cast<const s16x8*>(wqT + c_row * C_ + o0);
    s16x8 ao = *reinterpret_cast<const s16x8*>(wo_bf + c_row * C_ + o0);
#pragma unroll
    for (int nt = 0; nt < 5; ++nt) {
      int l = nt * 16 + r;
      s16x8 bk_ = *reinterpret_cast<const s16x8*>(kst + (b * LP + l) * C_ + o0);
      s16x8 bv_ = *reinterpret_cast<const s16x8*>(vst + (b * LP + l) * C_ + o0);
      a2[nt] = MFMA(aq, bk_, a2[nt]);
      av[nt] = MFMA(ao, bv_, av[nt]);
    }
  }
#pragma unroll
  for (int j = 0; j < 4; ++j) {
    int c = cc * 64 + w * 16 + h * 4 + j;
#pragma unroll
    for (int nt = 0; nt < 5; ++nt) {
      int l = nt * 16 + r;
      k2T[(b * LP + l) * C_ + c] = f2bf(a2[nt][j]);
      v2[(b * C_ + c) * LV + l] = f2bf(av[nt][j]);
    }
  }
  // zero v2 pad cols l in [80,96) (read by GEMM-H K=96; must not be garbage)
  {
    int c = cc * 64 + w * 16 + (lane >> 2);
    int l = 80 + (lane & 3) * 4;
    unsigned long long* p = (unsigned long long*)(v2 + ((long)(b * C_ + c)) * LV + l);
    *p = 0ull;
  }
  // t[l] = sum_o bq[o] * k_s[l][o]   (k_s already scaled; pad rows are zero)
  if (cc == 0 && threadIdx.x < LP) {
    int l = threadIdx.x;
    float acc = 0.f;
    for (int o8 = 0; o8 < C_; o8 += 8) {
      s16x8 kv = *reinterpret_cast<const s16x8*>(kst + (b * LP + l) * C_ + o8);
#pragma unroll
      for (int j = 0; j < 8; ++j) acc += bq[o8 + j] * bf2f((unsigned short)kv[j]);
    }
    tbuf[b * LP + l] = acc;
  }
}

// ---------------- MAIN: barrier-free GEMM-S (direct global A-fragments), 128-pos tile,
//                  512 threads, XCD swizzle, bf16 packed h store -------------------
__global__ __launch_bounds__(512, 3) void main_kernel(const float* __restrict__ x,
                                                      const unsigned short* __restrict__ k2T,
                                                      const unsigned short* __restrict__ v2,
                                                      const float* __restrict__ tbuf,
                                                      const float* __restrict__ bo,
                                                      float* __restrict__ accum,
                                                      float* __restrict__ hout) {
  __shared__ __align__(16) unsigned short wT[NT][WTP];   // 30720 B
  __shared__ float ch[2][C_][2];                         // 5120 B
  // XCD-chunked bijective swizzle: 864 = 8 * 108; XCD k gets one batch's tiles in order
  int bid = blockIdx.x;
  int swz = (bid & 7) * 108 + (bid >> 3);
  int b = swz / 108;
  int n0 = (swz % 108) * NT;
  int tid = threadIdx.x;
  int w = tid >> 6, lane = tid & 63, r = lane & 15, h = lane >> 4;
  const float* xg = x + (long)b * C_ * N_ + n0;
  const unsigned short* k2b = k2T + (long)b * LP * C_;
  // this lane's A-row pointer: x[c][n0 + w*16 + r] = xrow[c * N_]
  const float* xrow = xg + w * 16 + r;

  // ---- GEMM-S: s[16 rows/wave][80 l], K=320, direct global A-fragments, no barriers --
  f32x4 sacc[5] = {};
  float xvA[8], xvB[8];
#pragma unroll
  for (int j = 0; j < 8; ++j) xvA[j] = xrow[(long)(h * 8 + j) * N_];
#pragma unroll
  for (int j = 0; j < 8; ++j) xvB[j] = xrow[(long)(32 + h * 8 + j) * N_];

#define SCHUNK(KS, XV)                                                          \
  {                                                                             \
    s16x8 a;                                                                    \
    _Pragma("unroll") for (int j = 0; j < 8; ++j) a[j] = (short)f2bf(XV[j]);    \
    if (KS < 8) {                                                               \
      _Pragma("unroll") for (int j = 0; j < 8; ++j)                             \
          XV[j] = xrow[(long)((KS + 2) * 32 + h * 8 + j) * N_];                 \
    }                                                                           \
    _Pragma("unroll") for (int nt = 0; nt < 5; ++nt) {                          \
      s16x8 kf = *reinterpret_cast<const s16x8*>(                               \
          k2b + (nt * 16 + r) * C_ + KS * 32 + h * 8);                          \
      sacc[nt] = MFMA(a, kf, sacc[nt]);                                         \
    }                                                                           \
  }
  SCHUNK(0, xvA) SCHUNK(1, xvB) SCHUNK(2, xvA) SCHUNK(3, xvB) SCHUNK(4, xvA)
  SCHUNK(5, xvB) SCHUNK(6, xvA) SCHUNK(7, xvB) SCHUNK(8, xvA) SCHUNK(9, xvB)
#undef SCHUNK

  // ---- + t, softmax over l ----
#pragma unroll
  for (int nt = 0; nt < 5; ++nt) {
    float tl = tbuf[b * LP + nt * 16 + r];
#pragma unroll
    for (int j = 0; j < 4; ++j) sacc[nt][j] += tl;
  }
  bool maskpad = (r >= 13);   // col 64+r >= 77
#pragma unroll
  for (int j = 0; j < 4; ++j) {
    float m = -1e30f;
#pragma unroll
    for (int nt = 0; nt < 5; ++nt) {
      float v = (nt == 4 && maskpad) ? -1e30f : sacc[nt][j];
      m = fmaxf(m, v);
    }
    for (int d = 1; d < 16; d <<= 1) m = fmaxf(m, __shfl_xor(m, d));
    float e[5]; float sum = 0.f;
#pragma unroll
    for (int nt = 0; nt < 5; ++nt) {
      float v = (nt == 4 && maskpad) ? 0.f : __expf(sacc[nt][j] - m);
      e[nt] = v; sum += v;
    }
    for (int d = 1; d < 16; d <<= 1) sum += __shfl_xor(sum, d);
    float inv = 1.f / sum;
    int n = w * 16 + h * 4 + j;
#pragma unroll
    for (int nt = 0; nt < 5; ++nt) wT[n][nt * 16 + r] = f2bf(e[nt] * inv);
  }
  // zero wT cols 80..95 (K=96 contraction pad): 512 threads cover [128][16]
  {
    int row = tid >> 2, c0 = 80 + (tid & 3) * 4;
    *reinterpret_cast<unsigned*>(&wT[row][c0]) = 0u;
    *reinterpret_cast<unsigned*>(&wT[row][c0 + 2]) = 0u;
  }
  __syncthreads();

  // ---- GEMM-H: wave = (n-half nh, c-chunk cc4); h[80 c][64 n], K=96 over l ----
  int nh = w >> 2;          // 0/1: n-half
  int cc4 = w & 3;          // c-chunk of 80
  f32x4 acc[5][4] = {};
#pragma unroll
  for (int ks = 0; ks < 3; ++ks) {
    int l0 = ks * 32 + h * 8;
    s16x8 bfr[4];
#pragma unroll
    for (int nt = 0; nt < 4; ++nt)
      bfr[nt] = *reinterpret_cast<const s16x8*>(&wT[nh * 64 + nt * 16 + r][l0]);
#pragma unroll
    for (int mt = 0; mt < 5; ++mt) {
      int c = cc4 * 80 + mt * 16 + r;
      s16x8 a = *reinterpret_cast<const s16x8*>(v2 + ((long)(b * C_ + c)) * LV + l0);
#pragma unroll
      for (int nt = 0; nt < 4; ++nt) acc[mt][nt] = MFMA(a, bfr[nt], acc[mt][nt]);
    }
  }
  // ---- epilogue: + bo + residual (fp32 global, L2-hot), bf16 packed store, stats ----
#pragma unroll
  for (int mt = 0; mt < 5; ++mt) {
    int cb = cc4 * 80 + mt * 16 + h * 4;
    float bov[4];
#pragma unroll
    for (int j = 0; j < 4; ++j) bov[j] = bo[cb + j];
    float sv[4] = {0.f, 0.f, 0.f, 0.f}, sq[4] = {0.f, 0.f, 0.f, 0.f};
#pragma unroll
    for (int nt = 0; nt < 4; ++nt) {
      int n = nh * 64 + nt * 16 + r;
      const float* xp = xg + (long)cb * N_ + n;
#pragma unroll
      for (int j = 0; j < 4; ++j) {
        float val = acc[mt][nt][j] + bov[j] + xp[(long)j * N_];
        // bf16 packed store: chunk 2048 elems; bf16 of chunk sits in first 4 KB
        // of that chunk's 8 KB f32 region (self-contained for norm blocks)
        long e = ((long)b * C_ + cb + j) * N_ + n0 + n;
        *reinterpret_cast<unsigned short*>(
            (char*)hout + ((e >> 11) << 13) + ((e & 2047) << 1)) = f2bf(val);
        sv[j] += val; sq[j] += val * val;
      }
    }
#pragma unroll
    for (int j = 0; j < 4; ++j) {
      for (int d = 1; d < 16; d <<= 1) {
        sv[j] += __shfl_xor(sv[j], d);
        sq[j] += __shfl_xor(sq[j], d);
      }
      if (r == 0) { ch[nh][cb + j][0] = sv[j]; ch[nh][cb + j][1] = sq[j]; }
    }
  }
  __syncthreads();
  if (tid < 32) {
    float s0 = 0.f, s1 = 0.f;
#pragma unroll
    for (int i = 0; i < CPG; ++i) {
      int c = tid * CPG + i;
      s0 += ch[0][c][0] + ch[1][c][0];
      s1 += ch[0][c][1] + ch[1][c][1];
    }
    atomicAdd(&accum[b * 64 + tid * 2], s0);
    atomicAdd(&accum[b * 64 + tid * 2 + 1], s1);
  }
}

// ---------------- normalize + affine + swish: bf16 packed in -> f32 out -------------
__global__ __launch_bounds__(256) void norm_kernel(float* __restrict__ hout,
                                                   const float* __restrict__ accum,
                                                   const float* __restrict__ gamma,
                                                   const float* __restrict__ beta) {
  long idx0 = (long)blockIdx.x * 2048;
  int t = threadIdx.x;
  // thread t's 8 elements: idx0 + t*8 .. +8 (bf16 at chunk-local byte t*16)
  s16x8 hv = *reinterpret_cast<const s16x8*>((const char*)hout + idx0 * 4 + t * 16);
  __syncthreads();   // all bf16 reads complete before any f32 overwrite (intra-chunk)
  long idx = idx0 + (long)t * 8;
  int b = (int)(idx / ((long)C_ * N_));
  long rem = idx - (long)b * C_ * N_;
  int c = (int)(rem / N_);     // 8-run never crosses a channel row (8 | 13824)
  int g = c / CPG;
  float s0 = accum[b * 64 + g * 2], s1 = accum[b * 64 + g * 2 + 1];
  const float invc = 1.f / 138240.f;   // 1 / (CPG * N_)
  float mu = s0 * invc;
  float var = s1 * invc - mu * mu;
  float rstd = rsqrtf(var + EPS_);
  float ga = gamma[c], be = beta[c];
  f32x4 v0, v1;
#pragma unroll
  for (int q = 0; q < 4; ++q) {
    float y = (bf2f((unsigned short)hv[q]) - mu) * rstd * ga + be;
    v0[q] = y / (1.f + __expf(-y));
    float z = (bf2f((unsigned short)hv[q + 4]) - mu) * rstd * ga + be;
    v1[q] = z / (1.f + __expf(-z));
  }
  *reinterpret_cast<f32x4*>(hout + idx) = v0;
  *reinterpret_cast<f32x4*>(hout + idx + 4) = v1;
}

extern "C" void kernel_launch(void* const* d_in, const int* in_sizes, int n_in,
                              void* d_out, int out_size, void* d_ws, size_t ws_size,
                              hipStream_t stream) {
  const float* x     = (const float*)d_in[0];
  const float* ctx   = (const float*)d_in[1];
  const float* Wq    = (const float*)d_in[2];
  const float* bq    = (const float*)d_in[3];
  const float* Wk    = (const float*)d_in[4];
  const float* bk    = (const float*)d_in[5];
  const float* Wv    = (const float*)d_in[6];
  const float* bv    = (const float*)d_in[7];
  const float* Wo    = (const float*)d_in[8];
  const float* bo    = (const float*)d_in[9];
  const float* gamma = (const float*)d_in[10];
  const float* beta  = (const float*)d_in[11];
  float* out = (float*)d_out;
  char* ws = (char*)d_ws;

  float* accum = (float*)(ws + WS_ACCUM);
  float* tbuf  = (float*)(ws + WS_T);
  unsigned short* kst  = (unsigned short*)(ws + WS_KST);
  unsigned short* vst  = (unsigned short*)(ws + WS_VST);
  unsigned short* k2T  = (unsigned short*)(ws + WS_K2T);
  unsigned short* v2   = (unsigned short*)(ws + WS_V2);
  unsigned short* wqT  = (unsigned short*)(ws + WS_WQT);
  unsigned short* wo_b = (unsigned short*)(ws + WS_WO);

  prep_kernel<<<dim3(600), dim3(256), 0, stream>>>(Wq, Wo, ctx, Wk, bk, Wv, bv,
                                                   wqT, wo_b, kst, vst, (float*)ws);
  kv2_kernel<<<dim3(40), dim3(256), 0, stream>>>(wqT, wo_b, kst, vst, bq, tbuf, k2T, v2);
  main_kernel<<<dim3(864), dim3(512), 0, stream>>>(x, k2T, v2, tbuf, bo, accum, out);
  norm_kernel<<<dim3(17280), dim3(256), 0, stream>>>(out, accum, gamma, beta);
}